// Round 2
// baseline (400.635 us; speedup 1.0000x reference)
//
#include <hip/hip_runtime.h>
#include <math.h>

#define N   8192
#define NZ  256
#define NC  128
#define DT  0.1f

__device__ __forceinline__ float wave_reduce(float v) {
    #pragma unroll
    for (int off = 32; off > 0; off >>= 1)
        v += __shfl_down(v, off, 64);
    return v;
}

__device__ __forceinline__ float dot4(float4 a, float4 b) {
    return a.x * b.x + a.y * b.y + a.z * b.z + a.w * b.w;
}

// K1: r = tanh(x + b)
__global__ __launch_bounds__(256) void k1_r(const float* __restrict__ x,
                                            const float* __restrict__ b,
                                            float* __restrict__ r) {
    int i = blockIdx.x * blockDim.x + threadIdx.x;
    if (i < N) r[i] = tanhf(x[i] + b[i]);
}

// Block-per-row matvec helper pattern: 256 threads, each thread 8 float4s,
// wave_reduce then LDS reduce across the 4 waves.
__device__ __forceinline__ float block_row_dot(const float4* __restrict__ row4,
                                               const float4* __restrict__ v4) {
    int t = threadIdx.x;
    float acc = 0.f;
    #pragma unroll
    for (int j = 0; j < (N / 4) / 256; ++j) {   // 8 iters
        int idx = t + j * 256;
        acc += dot4(row4[idx], v4[idx]);
    }
    acc = wave_reduce(acc);
    __shared__ float part[4];
    int wave = t >> 6, lane = t & 63;
    if (lane == 0) part[wave] = acc;
    __syncthreads();
    return part[0] + part[1] + part[2] + part[3];
}

// K2: z = W_rz @ r. One block per row (NZ=256 blocks).
__global__ __launch_bounds__(256) void k2_z(const float* __restrict__ Wrz,
                                            const float* __restrict__ r,
                                            float* __restrict__ z) {
    int row = blockIdx.x;
    float d = block_row_dot((const float4*)(Wrz + (size_t)row * N),
                            (const float4*)r);
    if (threadIdx.x == 0) z[row] = d;
}

// K3: dx_i = W_rr[i].r + W_epsr[i].eps + W_zr[i].z + W_cr[i].c - x_i
//     x_new = x + DT*dx ; r_new = tanh(x_new + b). One wave per row.
__global__ __launch_bounds__(256) void k3_main(const float* __restrict__ Wrr,
                                               const float* __restrict__ Wepsr,
                                               const float* __restrict__ Wzr,
                                               const float* __restrict__ Wcr,
                                               const float* __restrict__ r,
                                               const float* __restrict__ eps,
                                               const float* __restrict__ z,
                                               const float* __restrict__ c,
                                               const float* __restrict__ x,
                                               const float* __restrict__ b,
                                               float* __restrict__ out) {
    int row  = (blockIdx.x * blockDim.x + threadIdx.x) >> 6;
    int lane = threadIdx.x & 63;
    if (row >= N) return;

    const float4* wr = (const float4*)(Wrr + (size_t)row * N);
    const float4* r4 = (const float4*)r;
    float acc = 0.f;
    #pragma unroll 8
    for (int k = 0; k < (N / 4) / 64; ++k) {   // 32 iters, unroll-by-8
        int idx = lane + k * 64;
        acc += dot4(wr[idx], r4[idx]);
    }
    // W_epsr[row] (256) . eps
    {
        const float4* we = (const float4*)(Wepsr + (size_t)row * NZ);
        const float4* e4 = (const float4*)eps;
        acc += dot4(we[lane], e4[lane]);
    }
    // W_zr[row] (256) . z
    {
        const float4* wz = (const float4*)(Wzr + (size_t)row * NZ);
        const float4* z4 = (const float4*)z;
        acc += dot4(wz[lane], z4[lane]);
    }
    // W_cr[row] (128) . c : lanes 0..31
    if (lane < NC / 4) {
        const float4* wc = (const float4*)(Wcr + (size_t)row * NC);
        const float4* c4 = (const float4*)c;
        acc += dot4(wc[lane], c4[lane]);
    }
    acc = wave_reduce(acc);
    if (lane == 0) {
        float xi = x[row];
        float dx = acc - xi;
        float xn = xi + DT * dx;
        float rn = tanhf(xn + b[row]);
        out[row]     = xn;   // x_new
        out[N + row] = rn;   // r_new
    }
}

// K4: z_new = W_rz @ r_new ; c_new = W_rc @ r_new ; eps_new = z_new - z_tilde
// One block per output row (NZ + NC = 384 blocks).
__global__ __launch_bounds__(256) void k4_heads(const float* __restrict__ Wrz,
                                                const float* __restrict__ Wrc,
                                                const float* __restrict__ rnew,
                                                const float* __restrict__ ztilde,
                                                float* __restrict__ out) {
    int row = blockIdx.x;
    const float* Wrow = (row < NZ) ? (Wrz + (size_t)row * N)
                                   : (Wrc + (size_t)(row - NZ) * N);
    float d = block_row_dot((const float4*)Wrow, (const float4*)rnew);
    if (threadIdx.x == 0) {
        if (row < NZ) {
            out[2 * N + row]           = d;                 // z_new
            out[2 * N + NZ + NC + row] = d - ztilde[row];   // eps_new
        } else {
            out[2 * N + NZ + (row - NZ)] = d;               // c_new
        }
    }
}

extern "C" void kernel_launch(void* const* d_in, const int* in_sizes, int n_in,
                              void* d_out, int out_size, void* d_ws, size_t ws_size,
                              hipStream_t stream) {
    const float* x      = (const float*)d_in[0];
    const float* eps    = (const float*)d_in[1];
    const float* c      = (const float*)d_in[2];
    const float* ztilde = (const float*)d_in[3];
    const float* Wrr    = (const float*)d_in[4];
    const float* Wzr    = (const float*)d_in[5];
    const float* Wcr    = (const float*)d_in[6];
    const float* Wepsr  = (const float*)d_in[7];
    const float* Wrz    = (const float*)d_in[8];
    const float* Wrc    = (const float*)d_in[9];
    const float* b      = (const float*)d_in[10];
    float* out = (float*)d_out;

    float* r = (float*)d_ws;        // N floats
    float* z = r + N;               // NZ floats

    k1_r<<<N / 256, 256, 0, stream>>>(x, b, r);
    k2_z<<<NZ, 256, 0, stream>>>(Wrz, r, z);
    k3_main<<<(N * 64) / 256, 256, 0, stream>>>(Wrr, Wepsr, Wzr, Wcr,
                                                r, eps, z, c, x, b, out);
    k4_heads<<<NZ + NC, 256, 0, stream>>>(Wrz, Wrc, out + N, ztilde, out);
}

// Round 4
// 379.980 us; speedup vs baseline: 1.0544x; 1.0544x over previous
//
#include <hip/hip_runtime.h>
#include <math.h>

#define N   8192
#define NZ  256
#define NC  128
#define DT  0.1f

typedef float fx4 __attribute__((ext_vector_type(4)));

__device__ __forceinline__ float wave_reduce(float v) {
    #pragma unroll
    for (int off = 32; off > 0; off >>= 1)
        v += __shfl_down(v, off, 64);
    return v;
}

__device__ __forceinline__ float dot4v(fx4 a, fx4 b) {
    return a.x * b.x + a.y * b.y + a.z * b.z + a.w * b.w;
}

// nontemporal 16B load via native ext_vector_type
__device__ __forceinline__ fx4 ntload4(const float* p) {
    return __builtin_nontemporal_load((const fx4*)p);
}
__device__ __forceinline__ fx4 ld4(const float* p) {
    return *(const fx4*)p;
}

// K1: r = tanh(x + b), float4-vectorized
__global__ __launch_bounds__(256) void k1_r(const float* __restrict__ x,
                                            const float* __restrict__ b,
                                            float* __restrict__ r) {
    int i = blockIdx.x * blockDim.x + threadIdx.x;
    fx4 xv = ld4(x + 4 * i), bv = ld4(b + 4 * i), rv;
    rv.x = tanhf(xv.x + bv.x);
    rv.y = tanhf(xv.y + bv.y);
    rv.z = tanhf(xv.z + bv.z);
    rv.w = tanhf(xv.w + bv.w);
    *(fx4*)(r + 4 * i) = rv;
}

// Block-per-row matvec: 256 threads, each thread 8 float4s of the row,
// wave_reduce then LDS reduce across the 4 waves. W rows loaded nontemporal.
__device__ __forceinline__ float block_row_dot(const float* __restrict__ row,
                                               const float* __restrict__ v) {
    int t = threadIdx.x;
    float acc = 0.f;
    #pragma unroll
    for (int j = 0; j < (N / 4) / 256; ++j) {   // 8 iters
        int idx = 4 * (t + j * 256);
        acc += dot4v(ntload4(row + idx), ld4(v + idx));
    }
    acc = wave_reduce(acc);
    __shared__ float part[4];
    int wave = t >> 6, lane = t & 63;
    if (lane == 0) part[wave] = acc;
    __syncthreads();
    return part[0] + part[1] + part[2] + part[3];
}

// K2: z = W_rz @ r. One block per row (NZ=256 blocks).
__global__ __launch_bounds__(256) void k2_z(const float* __restrict__ Wrz,
                                            const float* __restrict__ r,
                                            float* __restrict__ z) {
    int row = blockIdx.x;
    float d = block_row_dot(Wrz + (size_t)row * N, r);
    if (threadIdx.x == 0) z[row] = d;
}

// K3: dx_i = W_rr[i].r + W_epsr[i].eps + W_zr[i].z + W_cr[i].c - x_i
//     x_new = x + DT*dx ; r_new = tanh(x_new + b). One wave per row.
__global__ __launch_bounds__(256) void k3_main(const float* __restrict__ Wrr,
                                               const float* __restrict__ Wepsr,
                                               const float* __restrict__ Wzr,
                                               const float* __restrict__ Wcr,
                                               const float* __restrict__ r,
                                               const float* __restrict__ eps,
                                               const float* __restrict__ z,
                                               const float* __restrict__ c,
                                               const float* __restrict__ x,
                                               const float* __restrict__ b,
                                               float* __restrict__ out) {
    int row  = (blockIdx.x * blockDim.x + threadIdx.x) >> 6;
    int lane = threadIdx.x & 63;
    if (row >= N) return;

    const float* wr = Wrr + (size_t)row * N;
    float acc = 0.f;
    #pragma unroll 8
    for (int k = 0; k < (N / 4) / 64; ++k) {   // 32 iters, unroll-by-8
        int idx = 4 * (lane + k * 64);
        acc += dot4v(ntload4(wr + idx), ld4(r + idx));
    }
    {   // W_epsr[row] (256) . eps
        acc += dot4v(ntload4(Wepsr + (size_t)row * NZ + 4 * lane),
                     ld4(eps + 4 * lane));
    }
    {   // W_zr[row] (256) . z
        acc += dot4v(ntload4(Wzr + (size_t)row * NZ + 4 * lane),
                     ld4(z + 4 * lane));
    }
    if (lane < NC / 4) {   // W_cr[row] (128) . c
        acc += dot4v(ntload4(Wcr + (size_t)row * NC + 4 * lane),
                     ld4(c + 4 * lane));
    }
    acc = wave_reduce(acc);
    if (lane == 0) {
        float xi = x[row];
        float dx = acc - xi;
        float xn = xi + DT * dx;
        float rn = tanhf(xn + b[row]);
        out[row]     = xn;   // x_new
        out[N + row] = rn;   // r_new
    }
}

// K4: z_new = W_rz @ r_new ; c_new = W_rc @ r_new ; eps_new = z_new - z_tilde
// One block per output row (NZ + NC = 384 blocks).
__global__ __launch_bounds__(256) void k4_heads(const float* __restrict__ Wrz,
                                                const float* __restrict__ Wrc,
                                                const float* __restrict__ rnew,
                                                const float* __restrict__ ztilde,
                                                float* __restrict__ out) {
    int row = blockIdx.x;
    const float* Wrow = (row < NZ) ? (Wrz + (size_t)row * N)
                                   : (Wrc + (size_t)(row - NZ) * N);
    float d = block_row_dot(Wrow, rnew);
    if (threadIdx.x == 0) {
        if (row < NZ) {
            out[2 * N + row]           = d;                 // z_new
            out[2 * N + NZ + NC + row] = d - ztilde[row];   // eps_new
        } else {
            out[2 * N + NZ + (row - NZ)] = d;               // c_new
        }
    }
}

extern "C" void kernel_launch(void* const* d_in, const int* in_sizes, int n_in,
                              void* d_out, int out_size, void* d_ws, size_t ws_size,
                              hipStream_t stream) {
    const float* x      = (const float*)d_in[0];
    const float* eps    = (const float*)d_in[1];
    const float* c      = (const float*)d_in[2];
    const float* ztilde = (const float*)d_in[3];
    const float* Wrr    = (const float*)d_in[4];
    const float* Wzr    = (const float*)d_in[5];
    const float* Wcr    = (const float*)d_in[6];
    const float* Wepsr  = (const float*)d_in[7];
    const float* Wrz    = (const float*)d_in[8];
    const float* Wrc    = (const float*)d_in[9];
    const float* b      = (const float*)d_in[10];
    float* out = (float*)d_out;

    float* r = (float*)d_ws;        // N floats
    float* z = r + N;               // NZ floats

    k1_r<<<N / (256 * 4), 256, 0, stream>>>(x, b, r);
    k2_z<<<NZ, 256, 0, stream>>>(Wrz, r, z);
    k3_main<<<(N * 64) / 256, 256, 0, stream>>>(Wrr, Wepsr, Wzr, Wcr,
                                                r, eps, z, c, x, b, out);
    k4_heads<<<NZ + NC, 256, 0, stream>>>(Wrz, Wrc, out + N, ztilde, out);
}

// Round 5
// 377.661 us; speedup vs baseline: 1.0608x; 1.0061x over previous
//
#include <hip/hip_runtime.h>
#include <math.h>

#define N   8192
#define NZ  256
#define NC  128
#define DT  0.1f

typedef float fx4 __attribute__((ext_vector_type(4)));

__device__ __forceinline__ float wave_reduce(float v) {
    #pragma unroll
    for (int off = 32; off > 0; off >>= 1)
        v += __shfl_down(v, off, 64);
    return v;
}

__device__ __forceinline__ float dot4v(fx4 a, fx4 b) {
    return a.x * b.x + a.y * b.y + a.z * b.z + a.w * b.w;
}

// nontemporal 16B load via native ext_vector_type (W streams are single-use:
// bypass L2 so the hot r/x/b vectors stay resident)
__device__ __forceinline__ fx4 ntload4(const float* p) {
    return __builtin_nontemporal_load((const fx4*)p);
}
__device__ __forceinline__ fx4 ld4(const float* p) {
    return *(const fx4*)p;
}

// K1: r = tanh(x + b), float4-vectorized
__global__ __launch_bounds__(256) void k1_r(const float* __restrict__ x,
                                            const float* __restrict__ b,
                                            float* __restrict__ r) {
    int i = blockIdx.x * blockDim.x + threadIdx.x;
    fx4 xv = ld4(x + 4 * i), bv = ld4(b + 4 * i), rv;
    rv.x = tanhf(xv.x + bv.x);
    rv.y = tanhf(xv.y + bv.y);
    rv.z = tanhf(xv.z + bv.z);
    rv.w = tanhf(xv.w + bv.w);
    *(fx4*)(r + 4 * i) = rv;
}

// Block-per-row matvec: 256 threads, each thread 8 float4s of the row,
// wave_reduce then LDS reduce across the 4 waves. W rows loaded nontemporal.
__device__ __forceinline__ float block_row_dot(const float* __restrict__ row,
                                               const float* __restrict__ v) {
    int t = threadIdx.x;
    float acc = 0.f;
    #pragma unroll
    for (int j = 0; j < (N / 4) / 256; ++j) {   // 8 iters
        int idx = 4 * (t + j * 256);
        acc += dot4v(ntload4(row + idx), ld4(v + idx));
    }
    acc = wave_reduce(acc);
    __shared__ float part[4];
    int wave = t >> 6, lane = t & 63;
    if (lane == 0) part[wave] = acc;
    __syncthreads();
    return part[0] + part[1] + part[2] + part[3];
}

// K2: z = W_rz @ r. One block per row (NZ=256 blocks).
__global__ __launch_bounds__(256) void k2_z(const float* __restrict__ Wrz,
                                            const float* __restrict__ r,
                                            float* __restrict__ z) {
    int row = blockIdx.x;
    float d = block_row_dot(Wrz + (size_t)row * N, r);
    if (threadIdx.x == 0) z[row] = d;
}

// K3: dx_i = W_rr[i].r + W_epsr[i].eps + W_zr[i].z + W_cr[i].c - x_i
//     x_new = x + DT*dx ; r_new = tanh(x_new + b). One wave per row.
// unroll 16: ~256 B of W in flight per wave for deeper HBM pipelining.
__global__ __launch_bounds__(256) void k3_main(const float* __restrict__ Wrr,
                                               const float* __restrict__ Wepsr,
                                               const float* __restrict__ Wzr,
                                               const float* __restrict__ Wcr,
                                               const float* __restrict__ r,
                                               const float* __restrict__ eps,
                                               const float* __restrict__ z,
                                               const float* __restrict__ c,
                                               const float* __restrict__ x,
                                               const float* __restrict__ b,
                                               float* __restrict__ out) {
    int row  = (blockIdx.x * blockDim.x + threadIdx.x) >> 6;
    int lane = threadIdx.x & 63;
    if (row >= N) return;

    const float* wr = Wrr + (size_t)row * N;
    float acc = 0.f;
    #pragma unroll 16
    for (int k = 0; k < (N / 4) / 64; ++k) {   // 32 iters, unroll-by-16
        int idx = 4 * (lane + k * 64);
        acc += dot4v(ntload4(wr + idx), ld4(r + idx));
    }
    {   // W_epsr[row] (256) . eps
        acc += dot4v(ntload4(Wepsr + (size_t)row * NZ + 4 * lane),
                     ld4(eps + 4 * lane));
    }
    {   // W_zr[row] (256) . z
        acc += dot4v(ntload4(Wzr + (size_t)row * NZ + 4 * lane),
                     ld4(z + 4 * lane));
    }
    if (lane < NC / 4) {   // W_cr[row] (128) . c
        acc += dot4v(ntload4(Wcr + (size_t)row * NC + 4 * lane),
                     ld4(c + 4 * lane));
    }
    acc = wave_reduce(acc);
    if (lane == 0) {
        float xi = x[row];
        float dx = acc - xi;
        float xn = xi + DT * dx;
        float rn = tanhf(xn + b[row]);
        out[row]     = xn;   // x_new
        out[N + row] = rn;   // r_new
    }
}

// K4: z_new = W_rz @ r_new ; c_new = W_rc @ r_new ; eps_new = z_new - z_tilde
// One block per output row (NZ + NC = 384 blocks).
__global__ __launch_bounds__(256) void k4_heads(const float* __restrict__ Wrz,
                                                const float* __restrict__ Wrc,
                                                const float* __restrict__ rnew,
                                                const float* __restrict__ ztilde,
                                                float* __restrict__ out) {
    int row = blockIdx.x;
    const float* Wrow = (row < NZ) ? (Wrz + (size_t)row * N)
                                   : (Wrc + (size_t)(row - NZ) * N);
    float d = block_row_dot(Wrow, rnew);
    if (threadIdx.x == 0) {
        if (row < NZ) {
            out[2 * N + row]           = d;                 // z_new
            out[2 * N + NZ + NC + row] = d - ztilde[row];   // eps_new
        } else {
            out[2 * N + NZ + (row - NZ)] = d;               // c_new
        }
    }
}

extern "C" void kernel_launch(void* const* d_in, const int* in_sizes, int n_in,
                              void* d_out, int out_size, void* d_ws, size_t ws_size,
                              hipStream_t stream) {
    const float* x      = (const float*)d_in[0];
    const float* eps    = (const float*)d_in[1];
    const float* c      = (const float*)d_in[2];
    const float* ztilde = (const float*)d_in[3];
    const float* Wrr    = (const float*)d_in[4];
    const float* Wzr    = (const float*)d_in[5];
    const float* Wcr    = (const float*)d_in[6];
    const float* Wepsr  = (const float*)d_in[7];
    const float* Wrz    = (const float*)d_in[8];
    const float* Wrc    = (const float*)d_in[9];
    const float* b      = (const float*)d_in[10];
    float* out = (float*)d_out;

    float* r = (float*)d_ws;        // N floats
    float* z = r + N;               // NZ floats

    k1_r<<<N / (256 * 4), 256, 0, stream>>>(x, b, r);
    k2_z<<<NZ, 256, 0, stream>>>(Wrz, r, z);
    k3_main<<<(N * 64) / 256, 256, 0, stream>>>(Wrr, Wepsr, Wzr, Wcr,
                                                r, eps, z, c, x, b, out);
    k4_heads<<<NZ + NC, 256, 0, stream>>>(Wrz, Wrc, out + N, ztilde, out);
}